// Round 9
// baseline (101.842 us; speedup 1.0000x reference)
//
#include <hip/hip_runtime.h>
#include <math.h>

// P2V: out[b,dhw] = top2-margin over n of softmax_n( |s2| * exp(-|s1| * dist) )
// dist = |x|^2 + |g|^2 - 2 x.g
//
// Round 9: R8 accounting closed: VALU-occupancy-bound, v_exp_f32 = ~16 cyc
// exclusive issue. Two levers:
//  (1) s2a<=1 fast path: e^v = P(u)^2, P = deg-7 Taylor of e^{(Ct/2)u} with
//      per-thread folded coeffs (v = Ct*u <= s2a, so (Ct/2)u <= 0.5,
//      rel err ~3e-7). Softmax shift cancels: out = (e^v0 - e^v1)/S_raw.
//      -> 1 trans/n instead of 2.
//  (2) packed f32 (v_pk_fma/min/max) for the whole main pipe, enabled by a
//      pair-interleaved LDS table so float2 operands are adjacent VGPRs.
// Per 2n: 14 pk + 2 trans + 2 ds_read_b128. Predicted ~31 us.
//
// q_n = -c1|x_n|^2 + 2c1(x_n.g), c1 = log2e*|s1|; u = 2^q; v = Ct*u,
// Ct = |s2|*2^(-c1|g|^2). top-2 of v == top-2 of q.

#define LOG2E 1.44269504088896340736f
typedef float f2 __attribute__((ext_vector_type(2)));

__global__ __launch_bounds__(256, 4) void p2v_kernel(
    const float* __restrict__ xyz,   // (B=4, C=3, N=1024)
    const float* __restrict__ grid,  // (C=3, 32768)
    const float* __restrict__ s1,
    const float* __restrict__ s2,
    float* __restrict__ out)         // (B=4, 32768)
{
    // 512 slots x 32 B, pair-interleaved: slot(p,c) holds n0=8p+c, n1=n0+4:
    //   float4 A: {q0c, q1c, 2c1*x0, 2c1*x1}   (q*c = -c1|x|^2 const term)
    //   float4 B: {2c1*y0, 2c1*y1, 2c1*z0, 2c1*z1}
    __shared__ float4 T[1024];

    const int tid = threadIdx.x;
    const int b   = blockIdx.x >> 9;                  // 512 blocks per b
    const int k   = blockIdx.x & 511;
    const int dhw = (k << 6) + (tid >> 2);            // quad -> one output
    const int c   = tid & 3;                          // n-lane within quad

    const float s1a = fabsf(s1[0]);
    const float s2a = fabsf(s2[0]);
    const float c1  = LOG2E * s1a;

    // ---- staging: thread fills slots 2*tid, 2*tid+1 ----
    const float* xb = xyz + b * 3072;
    #pragma unroll
    for (int sidx = 2 * tid; sidx < 2 * tid + 2; ++sidx) {
        const int p = sidx >> 2, cc = sidx & 3;
        const int n0 = 8 * p + cc, n1 = n0 + 4;
        const float x0 = xb[n0], y0 = xb[1024 + n0], z0 = xb[2048 + n0];
        const float x1 = xb[n1], y1 = xb[1024 + n1], z1 = xb[2048 + n1];
        const float q0 = -c1 * fmaf(x0, x0, fmaf(y0, y0, z0 * z0));
        const float q1 = -c1 * fmaf(x1, x1, fmaf(y1, y1, z1 * z1));
        T[2 * sidx]     = make_float4(q0, q1, 2.f * c1 * x0, 2.f * c1 * x1);
        T[2 * sidx + 1] = make_float4(2.f * c1 * y0, 2.f * c1 * y1,
                                      2.f * c1 * z0, 2.f * c1 * z1);
    }
    __syncthreads();

    const float g0 = grid[dhw];
    const float g1 = grid[32768 + dhw];
    const float g2 = grid[65536 + dhw];
    const float Ct = s2a * __builtin_amdgcn_exp2f(
        -c1 * fmaf(g0, g0, fmaf(g1, g1, g2 * g2)));

    // per-thread poly coeffs: kk = (Ct/2)^k / k!  (used by fast path)
    const float r  = 0.5f * Ct;
    const float k1 = r;
    const float k2 = r * k1 * 0.5f;
    const float k3 = r * k2 * (1.f / 3.f);
    const float k4 = r * k3 * 0.25f;
    const float k5 = r * k4 * 0.2f;
    const float k6 = r * k5 * (1.f / 6.f);
    const float k7 = r * k6 * (1.f / 7.f);

    const float4* Tc = T + 2 * c;
    float t0s, t1s, S;

    if (s2a <= 1.0f) {
        // ---- fast path: 1 trans/n, packed main pipe ----
        const f2 g0v = {g0, g0}, g1v = {g1, g1}, g2v = {g2, g2};
        const f2 k1v = {k1, k1}, k2v = {k2, k2}, k3v = {k3, k3}, k4v = {k4, k4};
        const f2 k5v = {k5, k5}, k6v = {k6, k6}, k7v = {k7, k7};
        const f2 onev = {1.f, 1.f};
        f2 t0v = {-INFINITY, -INFINITY}, t1v = {-INFINITY, -INFINITY};
        f2 Sv = {0.f, 0.f};

        #pragma unroll 8
        for (int p = 0; p < 128; ++p) {
            const float4 r0 = Tc[8 * p];
            const float4 r1 = Tc[8 * p + 1];
            const f2 ax = {r0.x, r0.y}, ay = {r0.z, r0.w};
            const f2 az = {r1.x, r1.y}, aw = {r1.z, r1.w};
            const f2 q = __builtin_elementwise_fma(aw, g2v,
                         __builtin_elementwise_fma(az, g1v,
                         __builtin_elementwise_fma(ay, g0v, ax)));
            const f2 m = __builtin_elementwise_min(q, t0v);   // top-2 update
            t1v = __builtin_elementwise_max(t1v, m);
            t0v = __builtin_elementwise_max(t0v, q);
            f2 u;
            u.x = __builtin_amdgcn_exp2f(q.x);
            u.y = __builtin_amdgcn_exp2f(q.y);
            f2 P = __builtin_elementwise_fma(k7v, u, k6v);
            P = __builtin_elementwise_fma(P, u, k5v);
            P = __builtin_elementwise_fma(P, u, k4v);
            P = __builtin_elementwise_fma(P, u, k3v);
            P = __builtin_elementwise_fma(P, u, k2v);
            P = __builtin_elementwise_fma(P, u, k1v);
            P = __builtin_elementwise_fma(P, u, onev);        // P ~ e^{r*u}
            Sv = __builtin_elementwise_fma(P, P, Sv);         // += e^{Ct*u}
        }
        t0s = fmaxf(t0v.x, t0v.y);
        t1s = fmaxf(fminf(t0v.x, t0v.y), fmaxf(t1v.x, t1v.y));
        S   = Sv.x + Sv.y;
    } else {
        // ---- general fallback: shifted 2-exp path (any s2a) ----
        const float EC  = LOG2E * Ct;
        const float Ls2 = LOG2E * s2a;
        float t0E = -INFINITY, t1E = -INFINITY, t0O = -INFINITY, t1O = -INFINITY;
        float S0 = 0.f, S1 = 0.f;
        #pragma unroll 4
        for (int p = 0; p < 128; ++p) {
            const float4 r0 = Tc[8 * p];
            const float4 r1 = Tc[8 * p + 1];
            const float qe = fmaf(g2, r1.z, fmaf(g1, r1.x, fmaf(g0, r0.z, r0.x)));
            const float qo = fmaf(g2, r1.w, fmaf(g1, r1.y, fmaf(g0, r0.w, r0.y)));
            t1E = __builtin_amdgcn_fmed3f(t0E, t1E, qe); t0E = fmaxf(t0E, qe);
            t1O = __builtin_amdgcn_fmed3f(t0O, t1O, qo); t0O = fmaxf(t0O, qo);
            S0 += __builtin_amdgcn_exp2f(fmaf(EC, __builtin_amdgcn_exp2f(qe), -Ls2));
            S1 += __builtin_amdgcn_exp2f(fmaf(EC, __builtin_amdgcn_exp2f(qo), -Ls2));
        }
        t0s = fmaxf(t0E, t0O);
        t1s = fmaxf(fminf(t0E, t0O), fmaxf(t1E, t1O));
        S   = S0 + S1;
    }

    // ---- quad butterfly merge (t0, t1, S) ----
    #pragma unroll
    for (int m = 1; m <= 2; m <<= 1) {
        const float ot0 = __shfl_xor(t0s, m);
        const float ot1 = __shfl_xor(t1s, m);
        const float oS  = __shfl_xor(S, m);
        t1s = fmaxf(fminf(t0s, ot0), fmaxf(t1s, ot1));
        t0s = fmaxf(t0s, ot0);
        S  += oS;
    }

    if (c == 0) {
        float res;
        if (s2a <= 1.0f) {
            const float u0 = __builtin_amdgcn_exp2f(t0s);
            const float u1 = __builtin_amdgcn_exp2f(t1s);
            float P0 = fmaf(k7, u0, k6);
            P0 = fmaf(P0, u0, k5); P0 = fmaf(P0, u0, k4); P0 = fmaf(P0, u0, k3);
            P0 = fmaf(P0, u0, k2); P0 = fmaf(P0, u0, k1); P0 = fmaf(P0, u0, 1.f);
            float P1 = fmaf(k7, u1, k6);
            P1 = fmaf(P1, u1, k5); P1 = fmaf(P1, u1, k4); P1 = fmaf(P1, u1, k3);
            P1 = fmaf(P1, u1, k2); P1 = fmaf(P1, u1, k1); P1 = fmaf(P1, u1, 1.f);
            res = (P0 * P0 - P1 * P1) / S;   // (e^v0 - e^v1) / S_raw
        } else {
            const float EC  = LOG2E * Ct;
            const float Ls2 = LOG2E * s2a;
            const float u0 = __builtin_amdgcn_exp2f(t0s);
            const float u1 = __builtin_amdgcn_exp2f(t1s);
            const float w0 = __builtin_amdgcn_exp2f(fmaf(EC, u0, -Ls2));
            res = w0 * (1.f - __builtin_amdgcn_exp2f(EC * (u1 - u0))) / S;
        }
        out[b * 32768 + dhw] = res;
    }
}

extern "C" void kernel_launch(void* const* d_in, const int* in_sizes, int n_in,
                              void* d_out, int out_size, void* d_ws, size_t ws_size,
                              hipStream_t stream) {
    const float* xyz  = (const float*)d_in[0];
    const float* grid = (const float*)d_in[1];
    const float* s1   = (const float*)d_in[2];
    const float* s2   = (const float*)d_in[3];
    float* out        = (float*)d_out;
    hipLaunchKernelGGL(p2v_kernel, dim3(2048), dim3(256), 0, stream,
                       xyz, grid, s1, s2, out);
}

// Round 10
// 95.246 us; speedup vs baseline: 1.0693x; 1.0693x over previous
//
#include <hip/hip_runtime.h>
#include <math.h>

// P2V: out[b,dhw] = top2-margin over n of softmax_n( |s2| * exp(-|s1| * dist) )
// dist = |x|^2 + |g|^2 - 2 x.g
//
// Round 10: R8 structure exactly (it measured 0 bank conflicts, 46us), one
// change: kill the OUTER exp. Cost model (fits R2/R6/R8/R9):
//   cyc/n-wave = 2*N_main + 16*N_trans.  R8: 7 main + 2 trans = 46.
// Fast path (uniform s2a<=1): v = Ct*u in [0,1], so e^v = deg-4 minimax poly
// (Chebyshev on [0,1], abs err 2.8e-5) with Ct^k FOLDED into per-thread
// coeffs d_k -> Horner in u, no per-n mul, d0 hoisted out of the loop.
// Per n: 3 fma(q) + med3 + max + 4 fma = 9 main + 1 trans = 36 cyc. ~34us.
// NOTE (R9 lesson): packed f32 is NOT a lever on CDNA4 - scalar v_fma
// already saturates the fp32 pipe; pk costs 2x cycles for 2x work.
//
// Math: q_n = -c1|x_n|^2 + 2c1(x_n.g), c1=log2e*|s1|; u=2^q; v=Ct*u,
//   Ct=|s2|*2^(-c1|g|^2); top-2 of v == top-2 of q (monotone).
//   fast:    S = sum_n P(v_n), out = (Q(u0)u0 - Q(u1)u1)/S  (d0 cancels)
//   general: S = sum_n 2^(EC*2^q - Ls2), out = 2^(EC*u0-Ls2)(1-2^(EC(u1-u0)))/S

#define LOG2E 1.44269504088896340736f
// deg-4 minimax (Chebyshev) coeffs for e^x on [0,1], abs err <= 2.8e-5
#define PC0 1.0000247f
#define PC1 0.9987113f
#define PC2 0.5099871f
#define PC3 0.1399751f
#define PC4 0.0695533f

__global__ __launch_bounds__(256, 8) void p2v_kernel(
    const float* __restrict__ xyz,   // (B=4, C=3, N=1024)
    const float* __restrict__ grid,  // (C=3, 32768)
    const float* __restrict__ s1,
    const float* __restrict__ s2,
    float* __restrict__ out)         // (B=4, 32768)
{
    __shared__ float4 A[1024];       // 16 KB per-n table for this block's b

    const int tid = threadIdx.x;
    const int b   = blockIdx.x >> 9;                  // 512 blocks per b
    const int k   = blockIdx.x & 511;                 // 64 outputs per block
    const int dhw = (k << 6) + (tid >> 2);            // quad -> one output
    const int c   = tid & 3;                          // n-chunk within quad

    const float s1a = fabsf(s1[0]);
    const float s2a = fabsf(s2[0]);
    const float c1  = LOG2E * s1a;

    const float* xb = xyz + b * 3072;
    #pragma unroll
    for (int i = 0; i < 4; ++i) {
        const int n = tid + i * 256;
        const float x = xb[n], y = xb[1024 + n], z = xb[2048 + n];
        const float x2 = fmaf(x, x, fmaf(y, y, z * z));
        A[n] = make_float4(-c1 * x2, 2.f * c1 * x, 2.f * c1 * y, 2.f * c1 * z);
    }
    __syncthreads();

    const float g0 = grid[dhw];
    const float g1 = grid[32768 + dhw];
    const float g2 = grid[65536 + dhw];
    const float Ct = s2a * __builtin_amdgcn_exp2f(
        -c1 * fmaf(g0, g0, fmaf(g1, g1, g2 * g2)));

    const float4* Ac = A + c;
    float t0s, t1s, S;

    if (s2a <= 1.0f) {
        // ---- fast path: 1 trans/n; outer exp = Horner-in-u with folded Ct^k
        const float Ct2 = Ct * Ct;
        const float d1 = PC1 * Ct;
        const float d2 = PC2 * Ct2;
        const float d3 = PC3 * Ct2 * Ct;
        const float d4 = PC4 * Ct2 * Ct2;

        float t0E = -INFINITY, t1E = -INFINITY, t0O = -INFINITY, t1O = -INFINITY;
        float S0 = 128.f * PC0, S1 = 128.f * PC0;     // hoisted d0 terms

        #pragma unroll 8
        for (int i = 0; i < 256; ++i) {
            const float4 a = Ac[i << 2];              // A[4i + c], broadcast
            const float q = fmaf(g0, a.y, fmaf(g1, a.z, fmaf(g2, a.w, a.x)));
            if (i & 1) {
                t1O = __builtin_amdgcn_fmed3f(t0O, t1O, q);
                t0O = fmaxf(t0O, q);
            } else {
                t1E = __builtin_amdgcn_fmed3f(t0E, t1E, q);
                t0E = fmaxf(t0E, q);
            }
            const float u = __builtin_amdgcn_exp2f(q);
            float Q = fmaf(d4, u, d3);
            Q = fmaf(Q, u, d2);
            Q = fmaf(Q, u, d1);
            if (i & 1) S1 = fmaf(Q, u, S1); else S0 = fmaf(Q, u, S0);
        }
        t0s = fmaxf(t0E, t0O);
        t1s = fmaxf(fminf(t0E, t0O), fmaxf(t1E, t1O));
        S   = S0 + S1;
    } else {
        // ---- general fallback: R8's exact shifted 2-exp path ----
        const float EC  = LOG2E * Ct;
        const float Ls2 = LOG2E * s2a;
        float t0E = -INFINITY, t1E = -INFINITY, t0O = -INFINITY, t1O = -INFINITY;
        float S0 = 0.f, S1 = 0.f;
        #pragma unroll 8
        for (int i = 0; i < 256; ++i) {
            const float4 a = Ac[i << 2];
            const float q = fmaf(g0, a.y, fmaf(g1, a.z, fmaf(g2, a.w, a.x)));
            if (i & 1) {
                t1O = __builtin_amdgcn_fmed3f(t0O, t1O, q);
                t0O = fmaxf(t0O, q);
            } else {
                t1E = __builtin_amdgcn_fmed3f(t0E, t1E, q);
                t0E = fmaxf(t0E, q);
            }
            const float w = __builtin_amdgcn_exp2f(
                fmaf(EC, __builtin_amdgcn_exp2f(q), -Ls2));
            if (i & 1) S1 += w; else S0 += w;
        }
        t0s = fmaxf(t0E, t0O);
        t1s = fmaxf(fminf(t0E, t0O), fmaxf(t1E, t1O));
        S   = S0 + S1;
    }

    // ---- quad butterfly merge (t0, t1, S) ----
    #pragma unroll
    for (int m = 1; m <= 2; m <<= 1) {
        const float ot0 = __shfl_xor(t0s, m);
        const float ot1 = __shfl_xor(t1s, m);
        const float oS  = __shfl_xor(S, m);
        t1s = fmaxf(fminf(t0s, ot0), fmaxf(t1s, ot1));
        t0s = fmaxf(t0s, ot0);
        S  += oS;
    }

    if (c == 0) {
        float res;
        const float u0 = __builtin_amdgcn_exp2f(t0s);
        const float u1 = __builtin_amdgcn_exp2f(t1s);
        if (s2a <= 1.0f) {
            const float Ct2 = Ct * Ct;
            const float d1 = PC1 * Ct;
            const float d2 = PC2 * Ct2;
            const float d3 = PC3 * Ct2 * Ct;
            const float d4 = PC4 * Ct2 * Ct2;
            float Q0 = fmaf(d4, u0, d3);
            Q0 = fmaf(Q0, u0, d2); Q0 = fmaf(Q0, u0, d1);
            float Q1 = fmaf(d4, u1, d3);
            Q1 = fmaf(Q1, u1, d2); Q1 = fmaf(Q1, u1, d1);
            res = (Q0 * u0 - Q1 * u1) / S;    // d0 cancels exactly
        } else {
            const float EC  = LOG2E * Ct;
            const float Ls2 = LOG2E * s2a;
            const float w0 = __builtin_amdgcn_exp2f(fmaf(EC, u0, -Ls2));
            res = w0 * (1.f - __builtin_amdgcn_exp2f(EC * (u1 - u0))) / S;
        }
        out[b * 32768 + dhw] = res;
    }
}

extern "C" void kernel_launch(void* const* d_in, const int* in_sizes, int n_in,
                              void* d_out, int out_size, void* d_ws, size_t ws_size,
                              hipStream_t stream) {
    const float* xyz  = (const float*)d_in[0];
    const float* grid = (const float*)d_in[1];
    const float* s1   = (const float*)d_in[2];
    const float* s2   = (const float*)d_in[3];
    float* out        = (float*)d_out;
    hipLaunchKernelGGL(p2v_kernel, dim3(2048), dim3(256), 0, stream,
                       xyz, grid, s1, s2, out);
}